// Round 1
// baseline (137.633 us; speedup 1.0000x reference)
//
#include <hip/hip_runtime.h>
#include <math.h>

// Cosine similarity per matching row: out[b,n] = dot(a[b,n,:], b[b,n,:]) /
// (||a[b,n,:]|| * ||b[b,n,:]||), D = 256, eps-guarded per tf.l2_normalize.
//
// One 64-lane wave per row: lane i loads float4 #i of the 64 float4s in the
// row (fully coalesced, 16B/lane). Butterfly shuffle-reduce 3 sums, lane 0
// writes the result. Memory-bound: 134 MB read -> ~21 us floor at 6.3 TB/s.

#define EPS 1e-12f

__global__ __launch_bounds__(256) void cosine_rows_kernel(
    const float4* __restrict__ a4,
    const float4* __restrict__ b4,
    float* __restrict__ out,
    int nrows)
{
    const int wave = threadIdx.x >> 6;          // 0..3 within block
    const int lane = threadIdx.x & 63;
    const int row  = (blockIdx.x << 2) + wave;  // 4 rows per block
    if (row >= nrows) return;

    // Row = 256 floats = 64 float4s; lane i takes float4 i.
    const int idx = row * 64 + lane;
    const float4 av = a4[idx];
    const float4 bv = b4[idx];

    float saa = av.x * av.x + av.y * av.y + av.z * av.z + av.w * av.w;
    float sbb = bv.x * bv.x + bv.y * bv.y + bv.z * bv.z + bv.w * bv.w;
    float sab = av.x * bv.x + av.y * bv.y + av.z * bv.z + av.w * bv.w;

    // Wave-64 butterfly reduction (all lanes end with the full sums).
    #pragma unroll
    for (int off = 32; off > 0; off >>= 1) {
        saa += __shfl_xor(saa, off, 64);
        sbb += __shfl_xor(sbb, off, 64);
        sab += __shfl_xor(sab, off, 64);
    }

    if (lane == 0) {
        const float denom = sqrtf(fmaxf(saa, EPS)) * sqrtf(fmaxf(sbb, EPS));
        out[row] = sab / denom;
    }
}

extern "C" void kernel_launch(void* const* d_in, const int* in_sizes, int n_in,
                              void* d_out, int out_size, void* d_ws, size_t ws_size,
                              hipStream_t stream) {
    const float* a = (const float*)d_in[0];
    const float* b = (const float*)d_in[1];
    float* out = (float*)d_out;

    const int nrows = out_size;                 // 16 * 4096 = 65536
    const int blocks = (nrows + 3) / 4;         // 4 rows (waves) per block

    cosine_rows_kernel<<<blocks, 256, 0, stream>>>(
        (const float4*)a, (const float4*)b, out, nrows);
}